// Round 5
// baseline (319.777 us; speedup 1.0000x reference)
//
#include <hip/hip_runtime.h>
#include <stdint.h>

// MinGRU fused pipeline (round 4 resubmit — round 4 bench hit GPUAcquisitionTimeout):
//   GEMM: 256x128 block tile (wave tile 128x64, ratio 42.7 FLOP/LDS-byte),
//         BK=32, 2-phase double-buffered prefetch, slot-XOR LDS swizzle
//         (pre-swizzled global source + swizzled fragment read; linear LDS dest)
//   scans: CHK=256 (CL=16) -> 1024 blocks, VEC=4, uint2/float4 loads

#define B_    4
#define T_    4096
#define H_    1024
#define BT_   (B_*T_)       // 16384
#define EPSV  1e-5f
#define CHK   256           // chunks over T
#define CL    (T_/CHK)      // 16 steps per chunk
#define BM    256
#define BN    128
#define BK    32

typedef float  f32x4  __attribute__((ext_vector_type(4)));
typedef __bf16 bf16x8 __attribute__((ext_vector_type(8)));
typedef unsigned short u16;

__device__ __forceinline__ u16 f2bf(float f) {            // RNE f32->bf16
  uint32_t u = __builtin_bit_cast(uint32_t, f);
  u += 0x7fffu + ((u >> 16) & 1u);
  return (u16)(u >> 16);
}
__device__ __forceinline__ float bf2f(uint32_t u) {
  uint32_t v = (u & 0xffffu) << 16;
  return __builtin_bit_cast(float, v);
}
__device__ __forceinline__ void bf4(uint2 p, float* f) {  // 4 bf16 -> 4 f32
  f[0] = bf2f(p.x); f[1] = bf2f(p.x >> 16);
  f[2] = bf2f(p.y); f[3] = bf2f(p.y >> 16);
}

// ---------------- LayerNorm: one WAVE per row, shfl-only reduce ----------------
__global__ __launch_bounds__(256) void ln_kernel(
    const float* __restrict__ x, const float* __restrict__ gamma,
    const float* __restrict__ beta, u16* __restrict__ normed) {
  const int wid  = threadIdx.x >> 6, lane = threadIdx.x & 63;
  const int row  = blockIdx.x * 4 + wid;
  const float4* xr = reinterpret_cast<const float4*>(x + (size_t)row * H_);
  float4 v[4];
  float s = 0.0f, q = 0.0f;
  #pragma unroll
  for (int seg = 0; seg < 4; ++seg) {
    v[seg] = xr[seg * 64 + lane];
    s += v[seg].x + v[seg].y + v[seg].z + v[seg].w;
    q += v[seg].x*v[seg].x + v[seg].y*v[seg].y + v[seg].z*v[seg].z + v[seg].w*v[seg].w;
  }
  #pragma unroll
  for (int off = 1; off < 64; off <<= 1) {
    s += __shfl_xor(s, off);
    q += __shfl_xor(q, off);
  }
  const float mean = s * (1.0f / H_);
  const float var  = q * (1.0f / H_) - mean * mean;
  const float rstd = rsqrtf(var + EPSV);
  const float4* g4 = reinterpret_cast<const float4*>(gamma);
  const float4* b4 = reinterpret_cast<const float4*>(beta);
  uint2* o2 = reinterpret_cast<uint2*>(normed + (size_t)row * H_);
  #pragma unroll
  for (int seg = 0; seg < 4; ++seg) {
    const float4 g = g4[seg * 64 + lane];
    const float4 b = b4[seg * 64 + lane];
    uint2 o;
    o.x = (uint32_t)f2bf((v[seg].x - mean) * rstd * g.x + b.x)
        | ((uint32_t)f2bf((v[seg].y - mean) * rstd * g.y + b.y) << 16);
    o.y = (uint32_t)f2bf((v[seg].z - mean) * rstd * g.z + b.z)
        | ((uint32_t)f2bf((v[seg].w - mean) * rstd * g.w + b.w) << 16);
    o2[seg * 64 + lane] = o;
  }
}

// ---------------- weight pack: [Wg;Wc] f32 -> bf16 [2048][1024] ----------------
__global__ __launch_bounds__(256) void pack_kernel(
    const float* __restrict__ Wg, const float* __restrict__ Wc,
    u16* __restrict__ wpack) {
  const int idx4 = (blockIdx.x * 256 + threadIdx.x) * 4;
  const int n = idx4 >> 10;
  const int k = idx4 & 1023;
  const float* src = (n < 1024) ? (Wg + (size_t)n * 1024 + k)
                                : (Wc + (size_t)(n - 1024) * 1024 + k);
  const float4 v = *reinterpret_cast<const float4*>(src);
  uint2 o;
  o.x = (uint32_t)f2bf(v.x) | ((uint32_t)f2bf(v.y) << 16);
  o.y = (uint32_t)f2bf(v.z) | ((uint32_t)f2bf(v.w) << 16);
  *reinterpret_cast<uint2*>(wpack + idx4) = o;
}

// ---------------- GEMM 256x128 tile, BK=32, 4 waves (wave tile 128x64) --------
// Slot swizzle: LDS row = 4 slots of 16B; logical slot k stored at phys k^((row>>1)&3).
// Staged via pre-swizzled GLOBAL source (linear LDS dest); fragments read with the
// same XOR -> wave64 ds_read_b128 hits the 8-lane/bank-quad minimum (0 conflicts).
__global__ __launch_bounds__(256, 2) void gemm_kernel(
    const u16* __restrict__ A, const u16* __restrict__ Bw,
    const float* __restrict__ bg, const float* __restrict__ bc,
    u16* __restrict__ zbuf, u16* __restrict__ cbuf) {
  __shared__ u16 As[2][BM * BK];   // 16 KB per buf
  __shared__ u16 Bs[2][BN * BK];   //  8 KB per buf
  const int bid = blockIdx.x;
  const int nb  = (bid & 7) * 128 + (bid >> 3);   // XCD swizzle (1024 % 8 == 0)
  const int mt  = nb >> 4, nt = nb & 15;          // mt<64 row-tiles, nt<16 col-tiles
  const int tid = threadIdx.x;
  const int wid = tid >> 6, lane = tid & 63;
  const int wr  = wid >> 1, wcq = wid & 1;        // wave tile: rows wr*128, cols wcq*64
  const int frow = lane & 15;
  const int physslot = (lane >> 4) ^ ((frow >> 1) & 3);

  f32x4 acc[8][4] = {};

  // staging source pointers (global pre-swizzle): chunk c: row=c>>2, phys slot=c&3
  // holds global slot (c&3)^((row>>1)&3)
  const u16* aptr[4];
  const u16* bptr[2];
  #pragma unroll
  for (int i = 0; i < 4; ++i) {
    const int c = tid + 256 * i;
    const int row = c >> 2;
    const int sl = (c & 3) ^ ((row >> 1) & 3);
    aptr[i] = A + (size_t)(mt * BM + row) * 1024 + sl * 8;
  }
  #pragma unroll
  for (int i = 0; i < 2; ++i) {
    const int c = tid + 256 * i;
    const int row = c >> 2;
    const int sl = (c & 3) ^ ((row >> 1) & 3);
    bptr[i] = Bw + (size_t)(nt * BN + row) * 1024 + sl * 8;
  }

  auto stage = [&](int buf, int ks) {
    const int kk = ks * BK;
    #pragma unroll
    for (int i = 0; i < 4; ++i)
      __builtin_amdgcn_global_load_lds(
          (const __attribute__((address_space(1))) void*)(aptr[i] + kk),
          (__attribute__((address_space(3))) void*)&As[buf][(tid + 256 * i) * 8], 16, 0, 0);
    #pragma unroll
    for (int i = 0; i < 2; ++i)
      __builtin_amdgcn_global_load_lds(
          (const __attribute__((address_space(1))) void*)(bptr[i] + kk),
          (__attribute__((address_space(3))) void*)&Bs[buf][(tid + 256 * i) * 8], 16, 0, 0);
  };
  auto compute = [&](int buf) {
    bf16x8 bfr[4];
    #pragma unroll
    for (int n = 0; n < 4; ++n)
      bfr[n] = *reinterpret_cast<const bf16x8*>(
          &Bs[buf][(wcq * 64 + n * 16 + frow) * BK + physslot * 8]);
    #pragma unroll
    for (int m = 0; m < 8; ++m) {
      const bf16x8 am = *reinterpret_cast<const bf16x8*>(
          &As[buf][(wr * 128 + m * 16 + frow) * BK + physslot * 8]);
      #pragma unroll
      for (int n = 0; n < 4; ++n)
        acc[m][n] = __builtin_amdgcn_mfma_f32_16x16x32_bf16(am, bfr[n], acc[m][n], 0, 0, 0);
    }
  };

  stage(0, 0);
  __syncthreads();                 // buf0 ready
  int cur = 0;
  for (int ks = 0; ks < 31; ++ks) {
    stage(cur ^ 1, ks + 1);        // prefetch flies under compute
    compute(cur);
    __syncthreads();               // one barrier/iter
    cur ^= 1;
  }
  compute(cur);

  // epilogue: C/D layout col = lane&15, row = (lane>>4)*4 + r  [m89]
  const int r0 = (lane >> 4) * 4;
  const int col16 = lane & 15;
  const bool isz = (nt < 8);       // whole col-tile is z-half or c-half
  #pragma unroll
  for (int m = 0; m < 8; ++m) {
    #pragma unroll
    for (int n = 0; n < 4; ++n) {
      const int col = nt * BN + wcq * 64 + n * 16 + col16;
      #pragma unroll
      for (int r = 0; r < 4; ++r) {
        const int row = mt * BM + wr * 128 + m * 16 + r0 + r;   // bt index
        float v = acc[m][n][r];
        if (isz) {
          v += bg[col];
          v = 1.0f / (1.0f + __expf(-v));
          zbuf[(size_t)row * 1024 + col] = f2bf(v);
        } else {
          const int cc = col - 1024;
          v += bc[cc];
          cbuf[(size_t)row * 1024 + cc] = f2bf(v);
        }
      }
    }
  }
}

// ---------------- scan phase 1: per-chunk (prod a, partial h), VEC=4 ----------
__global__ __launch_bounds__(256) void scan1_kernel(
    const u16* __restrict__ zbuf, const u16* __restrict__ cbuf,
    float* __restrict__ Achk, float* __restrict__ Uchk) {
  const int bid   = blockIdx.x;            // [0, B_*CHK)
  const int chunk = bid & (CHK - 1);
  const int b     = bid >> 8;              // CHK=256
  const int o4    = threadIdx.x * 4;
  const size_t base = ((size_t)(b * T_ + chunk * CL)) * H_ + o4;
  float A[4] = {1.f, 1.f, 1.f, 1.f};
  float u[4] = {0.f, 0.f, 0.f, 0.f};
  #pragma unroll
  for (int t = 0; t < CL; ++t) {
    const size_t idx = base + (size_t)t * H_;
    const uint2 zp = *reinterpret_cast<const uint2*>(&zbuf[idx]);
    const uint2 cp = *reinterpret_cast<const uint2*>(&cbuf[idx]);
    float z[4], c[4];
    bf4(zp, z); bf4(cp, c);
    #pragma unroll
    for (int j = 0; j < 4; ++j) {
      const float a = 1.0f - z[j];
      A[j] *= a;
      u[j] = a * u[j] + z[j] * c[j];
    }
  }
  const int idx = (b * CHK + chunk) * H_ + o4;
  *reinterpret_cast<float4*>(&Achk[idx]) = make_float4(A[0], A[1], A[2], A[3]);
  *reinterpret_cast<float4*>(&Uchk[idx]) = make_float4(u[0], u[1], u[2], u[3]);
}

// ---------------- scan phase 2: cross-chunk prefix (tiny) ----------------
__global__ __launch_bounds__(256) void scan2_kernel(
    const float* __restrict__ Achk, const float* __restrict__ Uchk,
    float* __restrict__ Hin) {
  const int g = blockIdx.x * 256 + threadIdx.x;   // [0, B_*H_)
  const int b = g >> 10;
  const int o = g & 1023;
  float h = 0.0f;
  #pragma unroll 8
  for (int j = 0; j < CHK; ++j) {
    const int idx = (b * CHK + j) * H_ + o;
    Hin[idx] = h;                       // h BEFORE chunk j
    h = Achk[idx] * h + Uchk[idx];
  }
}

// ---------------- scan phase 3: replay with h_in, add residual, VEC=4 ---------
__global__ __launch_bounds__(256) void scan3_kernel(
    const u16* __restrict__ zbuf, const u16* __restrict__ cbuf,
    const float* __restrict__ Hin, const float* __restrict__ x,
    float* __restrict__ out) {
  const int bid   = blockIdx.x;
  const int chunk = bid & (CHK - 1);
  const int b     = bid >> 8;
  const int o4    = threadIdx.x * 4;
  const float4 hv = *reinterpret_cast<const float4*>(&Hin[(b * CHK + chunk) * H_ + o4]);
  float h[4] = {hv.x, hv.y, hv.z, hv.w};
  const size_t base = ((size_t)(b * T_ + chunk * CL)) * H_ + o4;
  #pragma unroll
  for (int t = 0; t < CL; ++t) {
    const size_t idx = base + (size_t)t * H_;
    const uint2 zp = *reinterpret_cast<const uint2*>(&zbuf[idx]);
    const uint2 cp = *reinterpret_cast<const uint2*>(&cbuf[idx]);
    const float4 xv = *reinterpret_cast<const float4*>(&x[idx]);
    float z[4], c[4];
    bf4(zp, z); bf4(cp, c);
    #pragma unroll
    for (int j = 0; j < 4; ++j)
      h[j] = (1.0f - z[j]) * h[j] + z[j] * c[j];
    *reinterpret_cast<float4*>(&out[idx]) =
        make_float4(h[0] + xv.x, h[1] + xv.y, h[2] + xv.z, h[3] + xv.w);
  }
}

extern "C" void kernel_launch(void* const* d_in, const int* in_sizes, int n_in,
                              void* d_out, int out_size, void* d_ws, size_t ws_size,
                              hipStream_t stream) {
  const float* x     = (const float*)d_in[0];
  const float* gamma = (const float*)d_in[1];
  const float* beta  = (const float*)d_in[2];
  const float* Wg    = (const float*)d_in[3];
  const float* bg    = (const float*)d_in[4];
  const float* Wc    = (const float*)d_in[5];
  const float* bc    = (const float*)d_in[6];
  float* out = (float*)d_out;

  char* ws = (char*)d_ws;
  u16*   normed = (u16*)(ws);                         // 32 MB (dead after gemm)
  u16*   wpack  = (u16*)(ws + 33554432ull);           //  4 MB
  u16*   zbuf   = (u16*)(ws + 37748736ull);           // 32 MB
  u16*   cbuf   = (u16*)(ws + 71303168ull);           // 32 MB
  // scan temporaries (4 MB each) overlay the dead `normed` region
  float* Achk   = (float*)(ws);
  float* Uchk   = (float*)(ws + 4194304ull);
  float* Hin    = (float*)(ws + 8388608ull);

  ln_kernel  <<<BT_/4, 256, 0, stream>>>(x, gamma, beta, normed);
  pack_kernel<<<2048,  256, 0, stream>>>(Wg, Wc, wpack);
  gemm_kernel<<<1024,  256, 0, stream>>>(normed, wpack, bg, bc, zbuf, cbuf);
  scan1_kernel<<<B_*CHK, 256, 0, stream>>>(zbuf, cbuf, Achk, Uchk);
  scan2_kernel<<<16,     256, 0, stream>>>(Achk, Uchk, Hin);
  scan3_kernel<<<B_*CHK, 256, 0, stream>>>(zbuf, cbuf, Hin, x, out);
}

// Round 7
// 291.409 us; speedup vs baseline: 1.0973x; 1.0973x over previous
//
#include <hip/hip_runtime.h>
#include <stdint.h>

// MinGRU fused pipeline (round 6 resubmit — round 6 bench hit GPUAcquisitionTimeout):
//   GEMM: 256x128 tile, BK=32, slot-XOR swizzle (0 conflicts, verified r5),
//         COUNTED-vmcnt pipeline: raw s_barrier + s_waitcnt vmcnt(6),
//         never draining to 0 in the main loop (T4, m218).
//   scan2 -> hierarchical: scan2ab (16-chunk groups + shfl-scan over 16 groups),
//         scan3 rolls <=15 chunk-(A,u) applications from its group head.

#define B_    4
#define T_    4096
#define H_    1024
#define BT_   (B_*T_)       // 16384
#define EPSV  1e-5f
#define CHK   256           // chunks over T
#define CL    (T_/CHK)      // 16 steps per chunk
#define NG    16            // chunk groups (16 chunks each)
#define BM    256
#define BN    128
#define BK    32

typedef float  f32x4  __attribute__((ext_vector_type(4)));
typedef __bf16 bf16x8 __attribute__((ext_vector_type(8)));
typedef unsigned short u16;

#define ASM_VMCNT(N) asm volatile("s_waitcnt vmcnt(" #N ")" ::: "memory")
#define ASM_BAR()    asm volatile("s_barrier" ::: "memory")

__device__ __forceinline__ u16 f2bf(float f) {            // RNE f32->bf16
  uint32_t u = __builtin_bit_cast(uint32_t, f);
  u += 0x7fffu + ((u >> 16) & 1u);
  return (u16)(u >> 16);
}
__device__ __forceinline__ float bf2f(uint32_t u) {
  uint32_t v = (u & 0xffffu) << 16;
  return __builtin_bit_cast(float, v);
}
__device__ __forceinline__ void bf4(uint2 p, float* f) {  // 4 bf16 -> 4 f32
  f[0] = bf2f(p.x); f[1] = bf2f(p.x >> 16);
  f[2] = bf2f(p.y); f[3] = bf2f(p.y >> 16);
}

// ---------------- LayerNorm: one WAVE per row, shfl-only reduce ----------------
__global__ __launch_bounds__(256) void ln_kernel(
    const float* __restrict__ x, const float* __restrict__ gamma,
    const float* __restrict__ beta, u16* __restrict__ normed) {
  const int wid  = threadIdx.x >> 6, lane = threadIdx.x & 63;
  const int row  = blockIdx.x * 4 + wid;
  const float4* xr = reinterpret_cast<const float4*>(x + (size_t)row * H_);
  float4 v[4];
  float s = 0.0f, q = 0.0f;
  #pragma unroll
  for (int seg = 0; seg < 4; ++seg) {
    v[seg] = xr[seg * 64 + lane];
    s += v[seg].x + v[seg].y + v[seg].z + v[seg].w;
    q += v[seg].x*v[seg].x + v[seg].y*v[seg].y + v[seg].z*v[seg].z + v[seg].w*v[seg].w;
  }
  #pragma unroll
  for (int off = 1; off < 64; off <<= 1) {
    s += __shfl_xor(s, off);
    q += __shfl_xor(q, off);
  }
  const float mean = s * (1.0f / H_);
  const float var  = q * (1.0f / H_) - mean * mean;
  const float rstd = rsqrtf(var + EPSV);
  const float4* g4 = reinterpret_cast<const float4*>(gamma);
  const float4* b4 = reinterpret_cast<const float4*>(beta);
  uint2* o2 = reinterpret_cast<uint2*>(normed + (size_t)row * H_);
  #pragma unroll
  for (int seg = 0; seg < 4; ++seg) {
    const float4 g = g4[seg * 64 + lane];
    const float4 b = b4[seg * 64 + lane];
    uint2 o;
    o.x = (uint32_t)f2bf((v[seg].x - mean) * rstd * g.x + b.x)
        | ((uint32_t)f2bf((v[seg].y - mean) * rstd * g.y + b.y) << 16);
    o.y = (uint32_t)f2bf((v[seg].z - mean) * rstd * g.z + b.z)
        | ((uint32_t)f2bf((v[seg].w - mean) * rstd * g.w + b.w) << 16);
    o2[seg * 64 + lane] = o;
  }
}

// ---------------- weight pack: [Wg;Wc] f32 -> bf16 [2048][1024] ----------------
__global__ __launch_bounds__(256) void pack_kernel(
    const float* __restrict__ Wg, const float* __restrict__ Wc,
    u16* __restrict__ wpack) {
  const int idx4 = (blockIdx.x * 256 + threadIdx.x) * 4;
  const int n = idx4 >> 10;
  const int k = idx4 & 1023;
  const float* src = (n < 1024) ? (Wg + (size_t)n * 1024 + k)
                                : (Wc + (size_t)(n - 1024) * 1024 + k);
  const float4 v = *reinterpret_cast<const float4*>(src);
  uint2 o;
  o.x = (uint32_t)f2bf(v.x) | ((uint32_t)f2bf(v.y) << 16);
  o.y = (uint32_t)f2bf(v.z) | ((uint32_t)f2bf(v.w) << 16);
  *reinterpret_cast<uint2*>(wpack + idx4) = o;
}

// ---------------- GEMM 256x128 tile, BK=32, 4 waves (wave tile 128x64) --------
// Slot swizzle: logical 16B slot k of row stored at phys k^((row>>1)&3); staged via
// pre-swizzled GLOBAL source (linear LDS dest) + swizzled fragment read. 0 conflicts
// (verified round 5). Main loop: counted vmcnt(6) + raw barriers, no full drain.
__global__ __launch_bounds__(256, 2) void gemm_kernel(
    const u16* __restrict__ A, const u16* __restrict__ Bw,
    const float* __restrict__ bg, const float* __restrict__ bc,
    u16* __restrict__ zbuf, u16* __restrict__ cbuf) {
  __shared__ u16 As[2][BM * BK];   // 16 KB per buf
  __shared__ u16 Bs[2][BN * BK];   //  8 KB per buf
  const int bid = blockIdx.x;
  const int nb  = (bid & 7) * 128 + (bid >> 3);   // XCD swizzle (1024 % 8 == 0)
  const int mt  = nb >> 4, nt = nb & 15;          // mt<64 row-tiles, nt<16 col-tiles
  const int tid = threadIdx.x;
  const int wid = tid >> 6, lane = tid & 63;
  const int wr  = wid >> 1, wcq = wid & 1;        // wave tile: rows wr*128, cols wcq*64
  const int frow = lane & 15;
  const int physslot = (lane >> 4) ^ ((frow >> 1) & 3);

  f32x4 acc[8][4] = {};

  // staging source pointers (global pre-swizzle): chunk c: row=c>>2, phys slot=c&3
  // holds global slot (c&3)^((row>>1)&3)
  const u16* aptr[4];
  const u16* bptr[2];
  #pragma unroll
  for (int i = 0; i < 4; ++i) {
    const int c = tid + 256 * i;
    const int row = c >> 2;
    const int sl = (c & 3) ^ ((row >> 1) & 3);
    aptr[i] = A + (size_t)(mt * BM + row) * 1024 + sl * 8;
  }
  #pragma unroll
  for (int i = 0; i < 2; ++i) {
    const int c = tid + 256 * i;
    const int row = c >> 2;
    const int sl = (c & 3) ^ ((row >> 1) & 3);
    bptr[i] = Bw + (size_t)(nt * BN + row) * 1024 + sl * 8;
  }

  auto stage = [&](int buf, int ks) {   // 6 global_load_lds per thread
    const int kk = ks * BK;
    #pragma unroll
    for (int i = 0; i < 4; ++i)
      __builtin_amdgcn_global_load_lds(
          (const __attribute__((address_space(1))) void*)(aptr[i] + kk),
          (__attribute__((address_space(3))) void*)&As[buf][(tid + 256 * i) * 8], 16, 0, 0);
    #pragma unroll
    for (int i = 0; i < 2; ++i)
      __builtin_amdgcn_global_load_lds(
          (const __attribute__((address_space(1))) void*)(bptr[i] + kk),
          (__attribute__((address_space(3))) void*)&Bs[buf][(tid + 256 * i) * 8], 16, 0, 0);
  };
  auto compute = [&](int buf) {
    bf16x8 bfr[4];
    #pragma unroll
    for (int n = 0; n < 4; ++n)
      bfr[n] = *reinterpret_cast<const bf16x8*>(
          &Bs[buf][(wcq * 64 + n * 16 + frow) * BK + physslot * 8]);
    #pragma unroll
    for (int m = 0; m < 8; ++m) {
      const bf16x8 am = *reinterpret_cast<const bf16x8*>(
          &As[buf][(wr * 128 + m * 16 + frow) * BK + physslot * 8]);
      #pragma unroll
      for (int n = 0; n < 4; ++n)
        acc[m][n] = __builtin_amdgcn_mfma_f32_16x16x32_bf16(am, bfr[n], acc[m][n], 0, 0, 0);
    }
  };

  // ---- counted-vmcnt pipeline: 2 stage batches (12 loads) always in flight ----
  stage(0, 0);
  stage(1, 1);
  int cur = 0;
  for (int ks = 0; ks < 30; ++ks) {
    ASM_VMCNT(6);                 // oldest batch (buf cur) landed; newest 6 fly on
    ASM_BAR();                    // all waves see buf[cur] complete
    compute(cur);
    ASM_BAR();                    // all waves done READING buf[cur]
    stage(cur, ks + 2);           // overwrite buf[cur] for K-step ks+2
    cur ^= 1;
  }
  ASM_VMCNT(6);  ASM_BAR();       // K-step 30 (6 loads for 31 still in flight)
  compute(cur);
  ASM_BAR();
  cur ^= 1;
  ASM_VMCNT(0);  ASM_BAR();       // K-step 31: final drain
  compute(cur);

  // epilogue: C/D layout col = lane&15, row = (lane>>4)*4 + r  [m89]
  const int r0 = (lane >> 4) * 4;
  const int col16 = lane & 15;
  const bool isz = (nt < 8);       // whole col-tile is z-half or c-half
  #pragma unroll
  for (int m = 0; m < 8; ++m) {
    #pragma unroll
    for (int n = 0; n < 4; ++n) {
      const int col = nt * BN + wcq * 64 + n * 16 + col16;
      #pragma unroll
      for (int r = 0; r < 4; ++r) {
        const int row = mt * BM + wr * 128 + m * 16 + r0 + r;   // bt index
        float v = acc[m][n][r];
        if (isz) {
          v += bg[col];
          v = 1.0f / (1.0f + __expf(-v));
          zbuf[(size_t)row * 1024 + col] = f2bf(v);
        } else {
          const int cc = col - 1024;
          v += bc[cc];
          cbuf[(size_t)row * 1024 + cc] = f2bf(v);
        }
      }
    }
  }
}

// ---------------- scan phase 1: per-chunk (prod a, partial h), VEC=4 ----------
__global__ __launch_bounds__(256) void scan1_kernel(
    const u16* __restrict__ zbuf, const u16* __restrict__ cbuf,
    float* __restrict__ Achk, float* __restrict__ Uchk) {
  const int bid   = blockIdx.x;            // [0, B_*CHK)
  const int chunk = bid & (CHK - 1);
  const int b     = bid >> 8;              // CHK=256
  const int o4    = threadIdx.x * 4;
  const size_t base = ((size_t)(b * T_ + chunk * CL)) * H_ + o4;
  float A[4] = {1.f, 1.f, 1.f, 1.f};
  float u[4] = {0.f, 0.f, 0.f, 0.f};
  #pragma unroll
  for (int t = 0; t < CL; ++t) {
    const size_t idx = base + (size_t)t * H_;
    const uint2 zp = *reinterpret_cast<const uint2*>(&zbuf[idx]);
    const uint2 cp = *reinterpret_cast<const uint2*>(&cbuf[idx]);
    float z[4], c[4];
    bf4(zp, z); bf4(cp, c);
    #pragma unroll
    for (int j = 0; j < 4; ++j) {
      const float a = 1.0f - z[j];
      A[j] *= a;
      u[j] = a * u[j] + z[j] * c[j];
    }
  }
  const int idx = (b * CHK + chunk) * H_ + o4;
  *reinterpret_cast<float4*>(&Achk[idx]) = make_float4(A[0], A[1], A[2], A[3]);
  *reinterpret_cast<float4*>(&Uchk[idx]) = make_float4(u[0], u[1], u[2], u[3]);
}

// ---- scan phase 2 (hierarchical): per-thread 16-chunk compose, then 16-lane
//      shfl Hillis-Steele scan over groups -> exclusive group head Hgrp --------
__global__ __launch_bounds__(256) void scan2ab_kernel(
    const float* __restrict__ Achk, const float* __restrict__ Uchk,
    float* __restrict__ Hgrp) {
  const int t    = blockIdx.x * 256 + threadIdx.x;  // [0, B_*H_*NG)
  const int b    = t >> 14;                         // H_*NG = 16384
  const int idx  = t & 16383;
  const int o    = idx >> 4;
  const int g    = idx & 15;
  const int lane = threadIdx.x & 63;

  // compose the 16 chunks of group g (time order)
  float A = 1.0f, u = 0.0f;
  #pragma unroll
  for (int c = 0; c < 16; ++c) {
    const int chunk = g * 16 + c;
    const int e = (b * CHK + chunk) * H_ + o;
    const float a = Achk[e];
    u = a * u + Uchk[e];
    A *= a;
  }
  // inclusive scan across the 16 group-lanes: combined = prev THEN cur
  #pragma unroll
  for (int d = 1; d < 16; d <<= 1) {
    const float Ap = __shfl_up(A, d, 16);
    const float up = __shfl_up(u, d, 16);
    if ((lane & 15) >= d) {
      u = A * up + u;
      A = A * Ap;
    }
  }
  // exclusive: h entering group g = inclusive u of group g-1 (h0 = 0)
  const float hg = __shfl_up(u, 1, 16);
  Hgrp[(b * NG + g) * H_ + o] = (g == 0) ? 0.0f : hg;
}

// ---------------- scan phase 3: roll from group head, replay, add residual ----
__global__ __launch_bounds__(256) void scan3_kernel(
    const u16* __restrict__ zbuf, const u16* __restrict__ cbuf,
    const float* __restrict__ Achk, const float* __restrict__ Uchk,
    const float* __restrict__ Hgrp, const float* __restrict__ x,
    float* __restrict__ out) {
  const int bid   = blockIdx.x;
  const int chunk = bid & (CHK - 1);
  const int b     = bid >> 8;
  const int g     = chunk >> 4;
  const int o4    = threadIdx.x * 4;

  float4 hv = *reinterpret_cast<const float4*>(&Hgrp[(b * NG + g) * H_ + o4]);
  float h[4] = {hv.x, hv.y, hv.z, hv.w};
  // roll forward over chunks [g*16, chunk) — at most 15 steps, Achk/Uchk L2-hot
  for (int jc = g * 16; jc < chunk; ++jc) {
    const int e = (b * CHK + jc) * H_ + o4;
    const float4 a4 = *reinterpret_cast<const float4*>(&Achk[e]);
    const float4 u4 = *reinterpret_cast<const float4*>(&Uchk[e]);
    h[0] = a4.x * h[0] + u4.x;
    h[1] = a4.y * h[1] + u4.y;
    h[2] = a4.z * h[2] + u4.z;
    h[3] = a4.w * h[3] + u4.w;
  }

  const size_t base = ((size_t)(b * T_ + chunk * CL)) * H_ + o4;
  #pragma unroll
  for (int t = 0; t < CL; ++t) {
    const size_t idx = base + (size_t)t * H_;
    const uint2 zp = *reinterpret_cast<const uint2*>(&zbuf[idx]);
    const uint2 cp = *reinterpret_cast<const uint2*>(&cbuf[idx]);
    const float4 xv = *reinterpret_cast<const float4*>(&x[idx]);
    float z[4], c[4];
    bf4(zp, z); bf4(cp, c);
    #pragma unroll
    for (int j = 0; j < 4; ++j)
      h[j] = (1.0f - z[j]) * h[j] + z[j] * c[j];
    *reinterpret_cast<float4*>(&out[idx]) =
        make_float4(h[0] + xv.x, h[1] + xv.y, h[2] + xv.z, h[3] + xv.w);
  }
}

extern "C" void kernel_launch(void* const* d_in, const int* in_sizes, int n_in,
                              void* d_out, int out_size, void* d_ws, size_t ws_size,
                              hipStream_t stream) {
  const float* x     = (const float*)d_in[0];
  const float* gamma = (const float*)d_in[1];
  const float* beta  = (const float*)d_in[2];
  const float* Wg    = (const float*)d_in[3];
  const float* bg    = (const float*)d_in[4];
  const float* Wc    = (const float*)d_in[5];
  const float* bc    = (const float*)d_in[6];
  float* out = (float*)d_out;

  char* ws = (char*)d_ws;
  u16*   normed = (u16*)(ws);                         // 32 MB (dead after gemm)
  u16*   wpack  = (u16*)(ws + 33554432ull);           //  4 MB
  u16*   zbuf   = (u16*)(ws + 37748736ull);           // 32 MB
  u16*   cbuf   = (u16*)(ws + 71303168ull);           // 32 MB
  // scan temporaries overlay the dead `normed` region
  float* Achk   = (float*)(ws);                       // 4 MB
  float* Uchk   = (float*)(ws + 4194304ull);          // 4 MB
  float* Hgrp   = (float*)(ws + 8388608ull);          // 256 KB

  ln_kernel  <<<BT_/4, 256, 0, stream>>>(x, gamma, beta, normed);
  pack_kernel<<<2048,  256, 0, stream>>>(Wg, Wc, wpack);
  gemm_kernel<<<1024,  256, 0, stream>>>(normed, wpack, bg, bc, zbuf, cbuf);
  scan1_kernel <<<B_*CHK, 256, 0, stream>>>(zbuf, cbuf, Achk, Uchk);
  scan2ab_kernel<<<(B_*H_*NG)/256, 256, 0, stream>>>(Achk, Uchk, Hgrp);
  scan3_kernel <<<B_*CHK, 256, 0, stream>>>(zbuf, cbuf, Achk, Uchk, Hgrp, x, out);
}